// Round 8
// baseline (172.112 us; speedup 1.0000x reference)
//
#include <hip/hip_runtime.h>

#define BN 4
#define NN 8192
#define EE 128
#define HH 4
#define DD 32
#define WW 33
#define MROWS (BN*NN)            // 32768
#define QELEMS (MROWS*EE)        // 4194304
#define WELEMS (EE*EE)           // 16384

typedef __bf16 bf16x8 __attribute__((ext_vector_type(8)));
typedef float f32x4 __attribute__((ext_vector_type(4)));
typedef unsigned short u16x8 __attribute__((ext_vector_type(8)));

static __device__ __forceinline__ unsigned short f2bf(float x){
    unsigned u = __float_as_uint(x);
    u += 0x7fffu + ((u >> 16) & 1u);
    return (unsigned short)(u >> 16);
}
static __device__ __forceinline__ float bf2f(unsigned short h){
    return __uint_as_float(((unsigned)h) << 16);
}
static __device__ __forceinline__ bf16x8 ld_bf8(const unsigned short* p){
    u16x8 v = *(const u16x8*)p;
    return __builtin_bit_cast(bf16x8, v);
}

// ---------------- prep: q fp32 -> bf16 hi/lo (once; removes split from GEMM) ----------------
__global__ void __launch_bounds__(256) prep_q(const float* __restrict__ q,
        unsigned short* __restrict__ qh, unsigned short* __restrict__ ql){
    int i = blockIdx.x*256 + threadIdx.x;       // float4 index
    float4 v = ((const float4*)q)[i];
    float vv[4] = {v.x, v.y, v.z, v.w};
    unsigned short h[4], l[4];
    #pragma unroll
    for (int j=0;j<4;j++){
        h[j] = f2bf(vv[j]);
        l[j] = f2bf(vv[j] - bf2f(h[j]));
    }
    *(ushort4*)(qh + (size_t)i*4) = make_ushort4(h[0],h[1],h[2],h[3]);
    *(ushort4*)(ql + (size_t)i*4) = make_ushort4(l[0],l[1],l[2],l[3]);
}

// ---------------- prep: weights fp32 -> bf16 hi/lo ----------------
__global__ void __launch_bounds__(256) prep_w(const float* __restrict__ wq, const float* __restrict__ wk,
        const float* __restrict__ wv, const float* __restrict__ wo,
        unsigned short* __restrict__ wh, unsigned short* __restrict__ wl){
    int i = blockIdx.x*256 + threadIdx.x;       // 0..65535
    int sel = i >> 14;
    const float* src = (sel==0)? wq : (sel==1)? wk : (sel==2)? wv : wo;
    float x = src[i & (WELEMS-1)];
    unsigned short h = f2bf(x);
    wh[i] = h;
    wl[i] = f2bf(x - bf2f(h));
}

// ---------------- unified projection GEMM: C = A @ W^T + bias ----------------
// A pre-split bf16 hi/lo. Block = 256 thr = 4 waves; wave wv owns cols
// [wv*32, wv*32+32) (B = 16 frags = 64 VGPR, loaded once). One projection per
// blockIdx.y. 64 rows/block, A double-buffered. ~155 VGPR -> 3 blocks/CU.
__global__ void __launch_bounds__(256,3) gemm_proj(
        const unsigned short* __restrict__ inh, const unsigned short* __restrict__ inl,
        const unsigned short* __restrict__ whb, const unsigned short* __restrict__ wlb,
        const float* __restrict__ b0, const float* __restrict__ b1, const float* __restrict__ b2,
        float* __restrict__ o0, float* __restrict__ o1, float* __restrict__ o2)
{
    const int wv = threadIdx.x >> 6;           // 0..3 -> col base wv*32
    const int lane = threadIdx.x & 63;
    const int m = lane & 15, g = lane >> 4;
    const int y = blockIdx.y;
    const int rowB = blockIdx.x * 64;

    const unsigned short* WH = whb + (size_t)y*WELEMS;
    const unsigned short* WL = wlb + (size_t)y*WELEMS;
    const float* bias = (y==0)? b0 : (y==1)? b1 : b2;
    float* outp = (y==0)? o0 : (y==1)? o1 : o2;

    // B fragments for two 16-col tiles
    bf16x8 bH[2][4], bL[2][4];
    #pragma unroll
    for (int c=0;c<2;c++){
        const unsigned short* WHp = WH + (size_t)(wv*32 + c*16 + m)*EE;
        const unsigned short* WLp = WL + (size_t)(wv*32 + c*16 + m)*EE;
        #pragma unroll
        for (int kc=0;kc<4;kc++){
            bH[c][kc] = ld_bf8(WHp + kc*32 + g*8);
            bL[c][kc] = ld_bf8(WLp + kc*32 + g*8);
        }
    }
    const float bias2[2] = { bias[wv*32+m], bias[wv*32+16+m] };

    bf16x8 fa[2][8];                            // [buf][kc]=hi, [buf][4+kc]=lo
    {
        const size_t ab = (size_t)(rowB + m)*EE;
        #pragma unroll
        for (int kc=0;kc<4;kc++){
            fa[0][kc]   = ld_bf8(inh + ab + kc*32 + g*8);
            fa[0][4+kc] = ld_bf8(inl + ab + kc*32 + g*8);
        }
    }
    #pragma unroll
    for (int rt=0; rt<4; rt++){
        const int row0 = rowB + rt*16;
        if (rt < 3){                            // prefetch next 16-row tile
            const size_t ab = (size_t)(row0 + 16 + m)*EE;
            #pragma unroll
            for (int kc=0;kc<4;kc++){
                fa[(rt+1)&1][kc]   = ld_bf8(inh + ab + kc*32 + g*8);
                fa[(rt+1)&1][4+kc] = ld_bf8(inl + ab + kc*32 + g*8);
            }
        }
        #pragma unroll
        for (int c=0;c<2;c++){
            f32x4 acc = {0.f,0.f,0.f,0.f};
            #pragma unroll
            for (int kc=0;kc<4;kc++){
                acc = __builtin_amdgcn_mfma_f32_16x16x32_bf16(fa[rt&1][kc],   bH[c][kc], acc, 0,0,0);
                acc = __builtin_amdgcn_mfma_f32_16x16x32_bf16(fa[rt&1][kc],   bL[c][kc], acc, 0,0,0);
                acc = __builtin_amdgcn_mfma_f32_16x16x32_bf16(fa[rt&1][4+kc], bH[c][kc], acc, 0,0,0);
            }
            float* op = outp + (size_t)(row0 + g*4)*EE + wv*32 + c*16 + m;
            #pragma unroll
            for (int r=0;r<4;r++) op[(size_t)r*EE] = acc[r] + bias2[c];
        }
    }
}

// ---------------- sliding-window attention, fp32 exact ----------------
// 4 threads per position (each owns 8 of D=32). Block = 256 thr = 64 positions
// of one (b,h). LDS 25.3 KB: K buffer (stride 33) is DEAD after the score
// phase, so the probs staging buffer aliases it (barrier in between) -> 6 blk/CU.
__global__ void __launch_bounds__(256) attn_kernel(const float* __restrict__ Qf,
        const float* __restrict__ Kf, const float* __restrict__ Vf,
        float* __restrict__ probs, unsigned short* __restrict__ ah, unsigned short* __restrict__ al)
{
    __shared__ float KP[96*33];                // K during scores; probs staging after
    __shared__ float Vl[96*33];
    const int t = threadIdx.x;
    const int bh = blockIdx.y;
    const int b = bh >> 2, h = bh & 3;
    const int n0 = blockIdx.x * 64;
    const size_t rowbase = (size_t)b * NN;

    // stage K/V rows [n0-16, n0+80) slice [h*32, h*32+32), zero-fill OOB
    #pragma unroll
    for (int i=0;i<3;i++){
        int idx = t + i*256;                   // 0..767
        int row = idx >> 3, q4 = idx & 7;
        int grow = n0 - 16 + row;
        float4 kv = make_float4(0.f,0.f,0.f,0.f);
        float4 vv = make_float4(0.f,0.f,0.f,0.f);
        if (grow >= 0 && grow < NN){
            size_t goff = (rowbase + grow)*EE + h*DD + q4*4;
            kv = *(const float4*)(Kf + goff);
            vv = *(const float4*)(Vf + goff);
        }
        int lo = row*33 + q4*4;
        *(float4*)(KP + lo) = kv;
        *(float4*)(Vl + lo) = vv;
    }
    __syncthreads();

    const int p = t >> 2, e = t & 3;           // position p, dim-quarter e
    const int n = n0 + p;

    float qr[8];
    {
        const float4* qp = (const float4*)(Qf + (rowbase + n)*EE + h*DD + e*8);
        float4 v0 = qp[0], v1 = qp[1];
        qr[0]=v0.x; qr[1]=v0.y; qr[2]=v0.z; qr[3]=v0.w;
        qr[4]=v1.x; qr[5]=v1.y; qr[6]=v1.z; qr[7]=v1.w;
    }

    float sc[WW];
    #pragma unroll
    for (int w=0; w<WW; w++){
        const float* kr = &KP[(p+w)*33 + e*8];
        float s = 0.f;
        #pragma unroll
        for (int k=0;k<8;k++) s = fmaf(qr[k], kr[k], s);
        sc[w] = s;
    }
    // quad-reduce: all 4 threads end with the full dot product
    #pragma unroll
    for (int w=0; w<WW; w++){
        float s = sc[w];
        s += __shfl_xor(s, 1);
        s += __shfl_xor(s, 2);
        sc[w] = s * 0.17677669529663687f;      // 1/sqrt(32)
    }

    // K reads done for ALL threads before probs staging overwrites KP
    __syncthreads();

    float mx = sc[0];
    #pragma unroll
    for (int w=1;w<WW;w++) mx = fmaxf(mx, sc[w]);
    float sum = 0.f;
    #pragma unroll
    for (int w=0;w<WW;w++){ sc[w] = __expf(sc[w]-mx); sum += sc[w]; }
    float inv = 1.f / sum;
    #pragma unroll
    for (int w=0;w<WW;w++) sc[w] *= inv;

    // probs -> LDS staging (alias of KP); quad splits 9+8+8+8, compile-time idx
    {
        float* pl = KP + p*WW;
        if (e==0){
            #pragma unroll
            for (int w=0;w<9;w++) pl[w] = sc[w];
        } else if (e==1){
            #pragma unroll
            for (int w=9;w<17;w++) pl[w] = sc[w];
        } else if (e==2){
            #pragma unroll
            for (int w=17;w<25;w++) pl[w] = sc[w];
        } else {
            #pragma unroll
            for (int w=25;w<WW;w++) pl[w] = sc[w];
        }
    }

    // PV over own 8 dims
    float acc[8];
    #pragma unroll
    for (int k=0;k<8;k++) acc[k]=0.f;
    #pragma unroll
    for (int w=0;w<WW;w++){
        const float* vr = &Vl[(p+w)*33 + e*8];
        float pw = sc[w];
        #pragma unroll
        for (int k=0;k<8;k++) acc[k] = fmaf(pw, vr[k], acc[k]);
    }

    unsigned short hi[8], lo2[8];
    #pragma unroll
    for (int k=0;k<8;k++){ hi[k]=f2bf(acc[k]); lo2[k]=f2bf(acc[k]-bf2f(hi[k])); }
    size_t aoff = (rowbase + n)*EE + h*DD + e*8;
    *(ushort4*)(ah + aoff)     = make_ushort4(hi[0],hi[1],hi[2],hi[3]);
    *(ushort4*)(ah + aoff + 4) = make_ushort4(hi[4],hi[5],hi[6],hi[7]);
    *(ushort4*)(al + aoff)     = make_ushort4(lo2[0],lo2[1],lo2[2],lo2[3]);
    *(ushort4*)(al + aoff + 4) = make_ushort4(lo2[4],lo2[5],lo2[6],lo2[7]);

    // coalesced probs flush: block's region is 64*33 = 2112 contiguous floats
    __syncthreads();
    float* pbase = probs + ((size_t)bh*NN + n0)*WW;
    #pragma unroll
    for (int i=0;i<9;i++){
        int idx = t + i*256;
        if (idx < 64*WW) pbase[idx] = KP[idx];
    }
}

extern "C" void kernel_launch(void* const* d_in, const int* in_sizes, int n_in,
                              void* d_out, int out_size, void* d_ws, size_t ws_size,
                              hipStream_t stream) {
    const float* q  = (const float*)d_in[0];
    const float* Wq = (const float*)d_in[1];  const float* bq = (const float*)d_in[2];
    const float* Wk = (const float*)d_in[3];  const float* bk = (const float*)d_in[4];
    const float* Wv = (const float*)d_in[5];  const float* bv = (const float*)d_in[6];
    const float* Wo = (const float*)d_in[7];  const float* bo = (const float*)d_in[8];

    float* out   = (float*)d_out;             // (B,N,E) = 4194304 floats
    float* probs = out + QELEMS;              // (B,H,N,W) = 4325376 floats

    // workspace carve (~84 MB)
    unsigned short* q_hi = (unsigned short*)d_ws;
    unsigned short* q_lo = q_hi + QELEMS;
    unsigned short* a_hi = q_lo + QELEMS;
    unsigned short* a_lo = a_hi + QELEMS;
    unsigned short* w_hi = a_lo + QELEMS;
    unsigned short* w_lo = w_hi + 4*WELEMS;
    float* Qf = (float*)(w_lo + 4*WELEMS);
    float* Kf = Qf + QELEMS;
    float* Vf = Kf + QELEMS;

    prep_q<<<QELEMS/4/256, 256, 0, stream>>>(q, q_hi, q_lo);
    prep_w<<<4*WELEMS/256, 256, 0, stream>>>(Wq, Wk, Wv, Wo, w_hi, w_lo);
    gemm_proj<<<dim3(MROWS/64, 3), 256, 0, stream>>>(q_hi, q_lo, w_hi, w_lo,
                                                     bq, bk, bv, Qf, Kf, Vf);
    attn_kernel<<<dim3(NN/64, BN*HH), 256, 0, stream>>>(Qf, Kf, Vf, probs, a_hi, a_lo);
    gemm_proj<<<dim3(MROWS/64, 1), 256, 0, stream>>>(a_hi, a_lo,
                                                     w_hi + 3*WELEMS, w_lo + 3*WELEMS,
                                                     bo, bo, bo, out, out, out);
}

// Round 9
// 149.681 us; speedup vs baseline: 1.1499x; 1.1499x over previous
//
#include <hip/hip_runtime.h>

#define BN 4
#define NN 8192
#define EE 128
#define HH 4
#define DD 32
#define WW 33
#define MROWS (BN*NN)            // 32768
#define QELEMS (MROWS*EE)        // 4194304
#define WELEMS (EE*EE)           // 16384

typedef __bf16 bf16x8 __attribute__((ext_vector_type(8)));
typedef float f32x4 __attribute__((ext_vector_type(4)));
typedef unsigned short u16x8 __attribute__((ext_vector_type(8)));

static __device__ __forceinline__ unsigned short f2bf(float x){
    unsigned u = __float_as_uint(x);
    u += 0x7fffu + ((u >> 16) & 1u);
    return (unsigned short)(u >> 16);
}
static __device__ __forceinline__ float bf2f(unsigned short h){
    return __uint_as_float(((unsigned)h) << 16);
}
static __device__ __forceinline__ bf16x8 ld_bf8(const unsigned short* p){
    u16x8 v = *(const u16x8*)p;
    return __builtin_bit_cast(bf16x8, v);
}

// ---------------- prep: weights fp32 -> bf16 hi/lo ----------------
__global__ void __launch_bounds__(256) prep_w(const float* __restrict__ wq, const float* __restrict__ wk,
        const float* __restrict__ wv, const float* __restrict__ wo,
        unsigned short* __restrict__ wh, unsigned short* __restrict__ wl){
    int i = blockIdx.x*256 + threadIdx.x;       // 0..65535
    int sel = i >> 14;
    const float* src = (sel==0)? wq : (sel==1)? wk : (sel==2)? wv : wo;
    float x = src[i & (WELEMS-1)];
    unsigned short h = f2bf(x);
    wh[i] = h;
    wl[i] = f2bf(x - bf2f(h));
}

// ================= fully fused: QKV (MFMA, halo recompute) -> attention (VALU,
// exact f32) -> Wo (MFMA). Block = 512 thr = 8 waves, 64 positions of one batch.
// LDS 132KB -> 1 block/CU. All intermediate tensors live in LDS only. =================
__global__ void __launch_bounds__(512,2) fused_kernel(
        const float* __restrict__ q,
        const unsigned short* __restrict__ wh, const unsigned short* __restrict__ wl,
        const float* __restrict__ bq, const float* __restrict__ bk, const float* __restrict__ bv_,
        const float* __restrict__ bo,
        float* __restrict__ out, float* __restrict__ probs)
{
    __shared__ float Kl[HH*96*33];   // 50688 B; later aliased as attn-out (u32 [64][132])
    __shared__ float Vl[HH*96*33];   // 50688 B
    __shared__ float Ql[HH*64*33];   // 33792 B; later aliased as P staging [4][64][33]

    const int t = threadIdx.x;
    const int wv = t >> 6;               // wave 0..7 -> col stripe wv*16
    const int lane = t & 63;
    const int m = lane & 15, g = lane >> 4;
    const int b = blockIdx.y;
    const int n0 = blockIdx.x * 64;
    const size_t qrow0 = (size_t)b * NN;

    // ---- QKV B-fragments (held in registers for the whole phase) ----
    bf16x8 bH[3][4], bL[3][4];
    #pragma unroll
    for (int i=0;i<3;i++){
        const unsigned short* WH = wh + i*WELEMS + (size_t)(wv*16+m)*EE;
        const unsigned short* WL = wl + i*WELEMS + (size_t)(wv*16+m)*EE;
        #pragma unroll
        for (int kc=0;kc<4;kc++){
            bH[i][kc] = ld_bf8(WH + kc*32 + g*8);
            bL[i][kc] = ld_bf8(WL + kc*32 + g*8);
        }
    }
    const float bias3[3] = { bq[wv*16+m], bk[wv*16+m], bv_[wv*16+m] };
    const int head = wv >> 1, dimb = (wv & 1) * 16;

    // ---- Phase A: QKV for halo rows [n0-16, n0+80), MFMA, results -> LDS ----
    float4 fa[2][8];
    {
        int grow = n0 - 16 + m;
        bool ok = (grow >= 0) && (grow < NN);
        const float* qp = q + (qrow0 + (ok ? grow : 0))*EE;
        #pragma unroll
        for (int kc=0;kc<4;kc++){
            fa[0][kc*2]   = ok ? *(const float4*)(qp + kc*32 + g*8)     : make_float4(0.f,0.f,0.f,0.f);
            fa[0][kc*2+1] = ok ? *(const float4*)(qp + kc*32 + g*8 + 4) : make_float4(0.f,0.f,0.f,0.f);
        }
    }
    #pragma unroll
    for (int tile=0; tile<6; tile++){
        if (tile < 5){                          // prefetch next halo tile
            int grow = n0 - 16 + (tile+1)*16 + m;
            bool ok = (grow >= 0) && (grow < NN);
            const float* qp = q + (qrow0 + (ok ? grow : 0))*EE;
            #pragma unroll
            for (int kc=0;kc<4;kc++){
                fa[(tile+1)&1][kc*2]   = ok ? *(const float4*)(qp + kc*32 + g*8)     : make_float4(0.f,0.f,0.f,0.f);
                fa[(tile+1)&1][kc*2+1] = ok ? *(const float4*)(qp + kc*32 + g*8 + 4) : make_float4(0.f,0.f,0.f,0.f);
            }
        }
        bf16x8 aH[4], aL[4];
        #pragma unroll
        for (int kc=0;kc<4;kc++){
            float4 v0 = fa[tile&1][kc*2], v1 = fa[tile&1][kc*2+1];
            float vvv[8] = {v0.x,v0.y,v0.z,v0.w,v1.x,v1.y,v1.z,v1.w};
            u16x8 hh, ll;
            #pragma unroll
            for (int j=0;j<8;j++){
                unsigned short hB = f2bf(vvv[j]);
                hh[j] = hB;
                ll[j] = f2bf(vvv[j] - bf2f(hB));
            }
            aH[kc] = __builtin_bit_cast(bf16x8, hh);
            aL[kc] = __builtin_bit_cast(bf16x8, ll);
        }
        #pragma unroll
        for (int i=0;i<3;i++){
            if (i==0 && (tile==0 || tile==5)) continue;   // Q needed only for rows 16..79
            f32x4 acc = {0.f,0.f,0.f,0.f};
            #pragma unroll
            for (int kc=0;kc<4;kc++){
                acc = __builtin_amdgcn_mfma_f32_16x16x32_bf16(aH[kc], bH[i][kc], acc, 0,0,0);
                acc = __builtin_amdgcn_mfma_f32_16x16x32_bf16(aH[kc], bL[i][kc], acc, 0,0,0);
                acc = __builtin_amdgcn_mfma_f32_16x16x32_bf16(aL[kc], bH[i][kc], acc, 0,0,0);
            }
            #pragma unroll
            for (int r=0;r<4;r++){
                int hrow = tile*16 + g*4 + r;             // 0..95
                int grow = n0 - 16 + hrow;
                bool inr = (grow >= 0) && (grow < NN);
                float val = acc[r] + (inr ? bias3[i] : 0.f);   // pad rows stay EXACT zero
                if (i==0)      Ql[(head*64 + hrow-16)*33 + dimb + m] = val;
                else if (i==1) Kl[(head*96 + hrow   )*33 + dimb + m] = val;
                else           Vl[(head*96 + hrow   )*33 + dimb + m] = val;
            }
        }
    }
    __syncthreads();

    // ---- Phase B: sliding-window attention, exact fp32 (2 thr per (pos,head)) ----
    const int pr = t >> 1, e = t & 1;        // pair id, dim-half
    const int p = pr & 63, h = pr >> 6;
    float qr[16];
    {
        const float* qlp = &Ql[(h*64 + p)*33 + e*16];
        #pragma unroll
        for (int k=0;k<16;k++) qr[k] = qlp[k];
    }
    float sc[WW];
    #pragma unroll
    for (int ww=0; ww<WW; ww++){
        const float* kr = &Kl[(h*96 + p + ww)*33 + e*16];
        float s = 0.f;
        #pragma unroll
        for (int k=0;k<16;k++) s = fmaf(qr[k], kr[k], s);
        sc[ww] = s;
    }
    #pragma unroll
    for (int ww=0; ww<WW; ww++)
        sc[ww] = (sc[ww] + __shfl_xor(sc[ww], 1)) * 0.17677669529663687f;  // 1/sqrt(32)

    __syncthreads();   // all K/Q LDS reads complete before those regions are reused

    float mx = sc[0];
    #pragma unroll
    for (int ww=1;ww<WW;ww++) mx = fmaxf(mx, sc[ww]);
    float sum = 0.f;
    #pragma unroll
    for (int ww=0;ww<WW;ww++){ sc[ww] = __expf(sc[ww]-mx); sum += sc[ww]; }
    float inv = 1.f / sum;
    #pragma unroll
    for (int ww=0;ww<WW;ww++) sc[ww] *= inv;

    // stage P into Ql alias (layout [h][p][w]); compile-time indices only
    float* Pst = Ql;
    {
        float* pl = Pst + (h*64 + p)*33;
        if (e==0){
            #pragma unroll
            for (int ww=0;ww<17;ww++) pl[ww] = sc[ww];
        } else {
            #pragma unroll
            for (int ww=17;ww<WW;ww++) pl[ww] = sc[ww];
        }
    }

    // PV over own 16 dims
    float pv[16];
    #pragma unroll
    for (int k=0;k<16;k++) pv[k]=0.f;
    #pragma unroll
    for (int ww=0;ww<WW;ww++){
        const float* vr = &Vl[(h*96 + p + ww)*33 + e*16];
        float pw = sc[ww];
        #pragma unroll
        for (int k=0;k<16;k++) pv[k] = fmaf(pw, vr[k], pv[k]);
    }

    // attn-out packed bf16 hi/lo -> Kl alias as u32 [64 rows][132]
    unsigned int* Au = (unsigned int*)Kl;
    {
        unsigned int* ap = Au + p*132 + h*32 + e*16;
        #pragma unroll
        for (int k=0;k<16;k++){
            unsigned short hB = f2bf(pv[k]);
            unsigned short lB = f2bf(pv[k] - bf2f(hB));
            ap[k] = ((unsigned)hB << 16) | (unsigned)lB;
        }
    }
    __syncthreads();

    // ---- Phase C: Wo fragments, probs flush, out = attnout @ Wo^T + bo ----
    bf16x8 cH[4], cL[4];
    {
        const unsigned short* WH = wh + 3*WELEMS + (size_t)(wv*16+m)*EE;
        const unsigned short* WL = wl + 3*WELEMS + (size_t)(wv*16+m)*EE;
        #pragma unroll
        for (int kc=0;kc<4;kc++){
            cH[kc] = ld_bf8(WH + kc*32 + g*8);
            cL[kc] = ld_bf8(WL + kc*32 + g*8);
        }
    }
    const float bov = bo[wv*16+m];

    // coalesced probs flush: 4 heads x 64 rows x 33 = 8448 floats
    #pragma unroll
    for (int i2=0;i2<17;i2++){
        int idx = t + i2*512;
        if (idx < HH*64*WW){
            int hh2 = idx / (64*WW);
            int rr  = idx - hh2*(64*WW);
            probs[((size_t)(b*HH + hh2)*NN + n0)*WW + rr] = Pst[idx];
        }
    }

    #pragma unroll
    for (int rt=0; rt<4; rt++){
        bf16x8 aH2[4], aL2[4];
        const unsigned int* ap = Au + (rt*16 + m)*132;
        #pragma unroll
        for (int kc=0;kc<4;kc++){
            const unsigned int* app = ap + kc*32 + g*8;
            u16x8 hh, ll;
            #pragma unroll
            for (int j=0;j<8;j++){
                unsigned int u = app[j];
                hh[j] = (unsigned short)(u >> 16);
                ll[j] = (unsigned short)(u & 0xffffu);
            }
            aH2[kc] = __builtin_bit_cast(bf16x8, hh);
            aL2[kc] = __builtin_bit_cast(bf16x8, ll);
        }
        f32x4 acc2 = {0.f,0.f,0.f,0.f};
        #pragma unroll
        for (int kc=0;kc<4;kc++){
            acc2 = __builtin_amdgcn_mfma_f32_16x16x32_bf16(aH2[kc], cH[kc], acc2, 0,0,0);
            acc2 = __builtin_amdgcn_mfma_f32_16x16x32_bf16(aH2[kc], cL[kc], acc2, 0,0,0);
            acc2 = __builtin_amdgcn_mfma_f32_16x16x32_bf16(aL2[kc], cH[kc], acc2, 0,0,0);
        }
        float* op = out + (qrow0 + n0 + rt*16 + g*4)*EE + wv*16 + m;
        #pragma unroll
        for (int r=0;r<4;r++) op[(size_t)r*EE] = acc2[r] + bov;
    }
}

extern "C" void kernel_launch(void* const* d_in, const int* in_sizes, int n_in,
                              void* d_out, int out_size, void* d_ws, size_t ws_size,
                              hipStream_t stream) {
    const float* q  = (const float*)d_in[0];
    const float* Wq = (const float*)d_in[1];  const float* bq = (const float*)d_in[2];
    const float* Wk = (const float*)d_in[3];  const float* bk = (const float*)d_in[4];
    const float* Wv = (const float*)d_in[5];  const float* bv = (const float*)d_in[6];
    const float* Wo = (const float*)d_in[7];  const float* bo = (const float*)d_in[8];

    float* out   = (float*)d_out;             // (B,N,E) = 4194304 floats
    float* probs = out + QELEMS;              // (B,H,N,W) = 4325376 floats

    // workspace: only the split weights (256 KB)
    unsigned short* w_hi = (unsigned short*)d_ws;
    unsigned short* w_lo = w_hi + 4*WELEMS;

    prep_w<<<4*WELEMS/256, 256, 0, stream>>>(Wq, Wk, Wv, Wo, w_hi, w_lo);
    fused_kernel<<<dim3(NN/64, BN), 512, 0, stream>>>(q, w_hi, w_lo,
                                                      bq, bk, bv, bo, out, probs);
}